// Round 4
// baseline (2439.377 us; speedup 1.0000x reference)
//
#include <hip/hip_runtime.h>
#include <math.h>

#define NE 160000
#define NN 10000
#define NP1 13
#define CG_TOTAL 573
#define CC_TOTAL 171
#define G_TOTAL 145

typedef __attribute__((ext_vector_type(8))) short bf16x8;
typedef __attribute__((ext_vector_type(4))) float f32x4;

// path metadata (l1,l2,l3) in reference enumeration order
constexpr int c_l1[NP1]   = {0,0,0,1,1,1,1,1,2,2,2,2,2};
constexpr int c_l2[NP1]   = {0,1,2,0,1,1,2,3,0,1,2,2,3};
constexpr int c_l3[NP1]   = {0,1,2,1,0,2,1,2,2,1,0,2,1};
constexpr int c_cgoff[NP1+1]= {0,1,10,35,44,53,98,143,248,273,318,343,468,573};
constexpr int c_ccoff[NP1+1]= {0,1,4,9,12,21,30,45,66,71,86,111,136,171};
constexpr int c_goff[NP1] = {0,1,4,9,18,21,36,45,60,85,100,105,130};
constexpr int YB[4] = {0,1,4,9};
constexpr int KB[3] = {0,1,4};
constexpr int IB[3] = {0,1,4};

// ---------------- static device scratch ----------------
__device__ float g_cg[640];
__device__ int   g_dec[160];
__device__ float g_ys[(size_t)NE*16];     // CSR order
__device__ float g_rad[(size_t)NE*8];     // CSR order
__device__ unsigned short g_hb0[(size_t)NE*64];  // CSR order
__device__ unsigned short g_hb1[(size_t)NE*64];  // CSR order
__device__ unsigned short g_Bp0[12*2*64*8];
__device__ unsigned short g_Bp1[52*2*64*8];
__device__ float g_acc0[(size_t)NN*576];
__device__ float g_acc1[(size_t)NN*576];
__device__ float g_h0[(size_t)NN*576];
__device__ int g_cnt[NN];
__device__ int g_cur[NN];
__device__ int g_off[NN+1];
__device__ int g_jof[NE];    // edge -> CSR slot
__device__ int g_snds[NE];   // CSR slot -> sender node
__device__ int g_specs[NE];  // CSR slot -> sender species

__device__ inline unsigned short f2bf(float f){
  unsigned u = __float_as_uint(f);
  unsigned r = (u + 0x7FFFu + ((u>>16)&1u)) >> 16;
  return (unsigned short)r;
}
__device__ inline float silu(float a){ return a/(1.f+expf(-a)); }

// ---------------- CG computation (device, double, parallel) ----------------
__device__ double dfact(int n){ double f=1.0; for(int i=2;i<=n;++i) f*=(double)i; return f; }

__device__ double cg_coef(int j1,int m1,int j2,int m2,int j3,int m3){
  if(m1+m2!=m3) return 0.0;
  double pref = sqrt((2.0*j3+1.0)*dfact(j3+j1-j2)*dfact(j3-j1+j2)*dfact(j1+j2-j3)/dfact(j1+j2+j3+1));
  pref *= sqrt(dfact(j3+m3)*dfact(j3-m3)*dfact(j1-m1)*dfact(j1+m1)*dfact(j2-m2)*dfact(j2+m2));
  double s=0.0;
  for(int k=0;k<=j1+j2-j3;++k){
    int d0=k, d1=j1+j2-j3-k, d2=j1-m1-k, d3=j2+m2-k, d4=j3-j2+m1+k, d5=j3-j1-m2+k;
    if(d1<0||d2<0||d3<0||d4<0||d5<0) continue;
    double denom = dfact(d0)*dfact(d1)*dfact(d2)*dfact(d3)*dfact(d4)*dfact(d5);
    s += ((k&1)? -1.0:1.0)/denom;
  }
  return pref*s;
}

__device__ inline void rb_elem(int l, int i, int j, double& re, double& im){
  re=0.0; im=0.0;
  int mp = i - l;
  const double is2 = 0.70710678118654752440;
  if(mp>0){
    if(j==l+mp) re = ((mp&1)? -1.0:1.0)*is2;
    else if(j==l-mp) re = is2;
  } else if(mp==0){
    if(j==l) re = 1.0;
  } else {
    int m=-mp;
    if(j==l-m) im = is2;
    else if(j==l+m) im = -(((m&1)?-1.0:1.0))*is2;
  }
}

__global__ __launch_bounds__(1024) void k_cg(){
  __shared__ double s_cc[CC_TOTAL];
  __shared__ double s_crr[CG_TOTAL];
  __shared__ double s_cri[CG_TOTAL];
  __shared__ double s_inv[NP1];
  __shared__ int    s_useR[NP1];
  int tid = threadIdx.x;

  if(tid==0){
    int r=0;
    for(int q=0;q<NP1;q++){
      int l1=c_l1[q], l2=c_l2[q], l3=c_l3[q];
      int d1=2*l1+1, d2=2*l2+1, d3=2*l3+1;
      for(int i=0;i<d1;i++)for(int k=0;k<d3;k++){
        int cgs = c_cgoff[q] + i*d2*d3 + k;
        g_dec[r++] = cgs | (YB[l2]<<10) | (d2<<14) | (d3<<17);
      }
    }
  }

  if(tid < CC_TOTAL){
    int p=0; while(tid >= c_ccoff[p+1]) p++;
    int r = tid - c_ccoff[p];
    int l1=c_l1[p], l2=c_l2[p], l3=c_l3[p];
    int d2=2*l2+1;
    int ai = r/d2, bi = r - ai*d2;
    int a = ai - l1, b = bi - l2, c = a + b;
    double v = 0.0;
    if(c >= -l3 && c <= l3) v = cg_coef(l1,a,l2,b,l3,c);
    s_cc[tid] = v;
  }
  __syncthreads();

  if(tid < CG_TOTAL){
    int p=0; while(tid >= c_cgoff[p+1]) p++;
    int r = tid - c_cgoff[p];
    int l1=c_l1[p], l2=c_l2[p], l3=c_l3[p];
    int d2=2*l2+1, d3=2*l3+1;
    int i = r/(d2*d3), rem = r - i*(d2*d3);
    int j = rem/d3, k = rem - j*d3;
    double accr=0.0, acci=0.0;
    int d1=2*l1+1;
    for(int ai=0; ai<d1; ai++){
      double a1r,a1i; rb_elem(l1,i,ai,a1r,a1i);
      if(a1r==0.0 && a1i==0.0) continue;
      for(int bi=0; bi<d2; bi++){
        double cc = s_cc[c_ccoff[p] + ai*d2 + bi];
        if(cc==0.0) continue;
        int ci = (ai - l1) + (bi - l2) + l3;
        if(ci < 0 || ci >= d3) continue;
        double a2r,a2i; rb_elem(l2,j,bi,a2r,a2i);
        if(a2r==0.0 && a2i==0.0) continue;
        double a3r,a3i; rb_elem(l3,k,ci,a3r,a3i);
        a3i = -a3i;
        double p12r = a1r*a2r - a1i*a2i;
        double p12i = a1r*a2i + a1i*a2r;
        accr += (p12r*a3r - p12i*a3i)*cc;
        acci += (p12r*a3i + p12i*a3r)*cc;
      }
    }
    s_crr[tid] = accr;
    s_cri[tid] = acci;
  }
  __syncthreads();

  if(tid < NP1){
    int beg=c_cgoff[tid], end=c_cgoff[tid+1];
    double sr=0.0, si=0.0;
    for(int t=beg;t<end;t++){ sr += fabs(s_crr[t]); si += fabs(s_cri[t]); }
    int useR = (sr>=si);
    double nrm=0.0;
    for(int t=beg;t<end;t++){ double v = useR? s_crr[t] : s_cri[t]; nrm += v*v; }
    nrm = sqrt(nrm); if(nrm<1e-12) nrm=1e-12;
    s_useR[tid]=useR; s_inv[tid]=1.0/nrm;
  }
  __syncthreads();

  if(tid < CG_TOTAL){
    int p=0; while(tid >= c_cgoff[p+1]) p++;
    double v = s_useR[p]? s_crr[tid] : s_cri[tid];
    g_cg[tid] = (float)(v*s_inv[p]);
  }
}

// ---------------- CSR build ----------------
__global__ void k_zero(){
  int i = blockIdx.x*256 + threadIdx.x;
  if(i<NN){ g_cnt[i]=0; g_cur[i]=0; }
}

__global__ void k_hist(const int* __restrict__ rcv){
  int e = blockIdx.x*256 + threadIdx.x;
  if(e<NE) atomicAdd(&g_cnt[rcv[e]], 1);
}

__global__ void k_scan(){
  __shared__ int lds[1024];
  int t = threadIdx.x;
  int base = t*10;
  int s = 0;
  for(int i=0;i<10;i++){ int idx=base+i; if(idx<NN) s += g_cnt[idx]; }
  lds[t]=s; __syncthreads();
  for(int o=1;o<1024;o<<=1){
    int v = (t>=o)? lds[t-o] : 0;
    __syncthreads();
    lds[t]+=v;
    __syncthreads();
  }
  int run = lds[t]-s;
  for(int i=0;i<10;i++){ int idx=base+i; if(idx<NN){ g_off[idx]=run; run+=g_cnt[idx]; } }
  if(t==0) g_off[NN]=NE;
}

__global__ void k_scatter(const int* __restrict__ rcv, const int* __restrict__ snd,
                          const int* __restrict__ spec){
  int e = blockIdx.x*256 + threadIdx.x;
  if(e<NE){
    int r = rcv[e];
    int p = atomicAdd(&g_cur[r],1);
    int j = g_off[r]+p;
    g_jof[e] = j;
    int s = snd[e];
    g_snds[j] = s;
    g_specs[j] = spec[s];
  }
}

// ---------------- edge geometry + radial basis (writes CSR slots) ----------------
__global__ void k_edge(const float* __restrict__ pos, const int* __restrict__ snd,
                       const int* __restrict__ rcv){
  int e = blockIdx.x*blockDim.x + threadIdx.x;
  if(e>=NE) return;
  int s=snd[e], r=rcv[e];
  int j=g_jof[e];
  float dx=pos[r*3+0]-pos[s*3+0];
  float dy=pos[r*3+1]-pos[s*3+1];
  float dz=pos[r*3+2]-pos[s*3+2];
  float rr = sqrtf(dx*dx+dy*dy+dz*dz + 1e-12f);
  float x=dx/rr, y=dy/rr, z=dz/rr;
  float Y[16];
  Y[0]=1.f;
  const float s3=1.7320508075688772f;
  Y[1]=s3*y; Y[2]=s3*z; Y[3]=s3*x;
  const float s15=3.872983346207417f;
  const float s5h=1.118033988749895f;
  Y[4]=s15*x*y; Y[5]=s15*y*z; Y[6]=s5h*(3.f*z*z-1.f); Y[7]=s15*x*z; Y[8]=0.5f*s15*(x*x-y*y);
  const float s35_8=2.0916500663351889f;
  const float s105=10.246950765959598f;
  const float s21_8=1.6201851746019651f;
  const float s7h=1.3228756555322954f;
  Y[9]=s35_8*y*(3.f*x*x-y*y);
  Y[10]=s105*x*y*z;
  Y[11]=s21_8*y*(5.f*z*z-1.f);
  Y[12]=s7h*z*(5.f*z*z-3.f);
  Y[13]=s21_8*x*(5.f*z*z-1.f);
  Y[14]=0.5f*s105*z*(x*x-y*y);
  Y[15]=s35_8*x*(x*x-3.f*y*y);
  #pragma unroll
  for(int i=0;i<16;i++) g_ys[(size_t)j*16+i]=Y[i];
  float t = 2.f*(1.f - rr*0.2f);
  float env = (t>0.f)? 1.9784655248401538f*expf(-1.f/t) : 0.f;
  float rs = fmaxf(rr,1e-6f);
  const float sq25 = 0.6324555320336759f;
  float pre = sq25/rs * env;
  const float pi5 = 0.6283185307179586f;
  #pragma unroll
  for(int b=0;b<8;b++){
    g_rad[(size_t)j*8+b] = pre * sinf((float)(b+1)*pi5*rs);
  }
}

// ---------------- hidden = silu(rad@W1), bf16, CSR order ----------------
__global__ __launch_bounds__(256) void k_hidden(const float* __restrict__ W1a,
                                                const float* __restrict__ W1b){
  int idx = blockIdx.x*256 + threadIdx.x;   // idx = slot*64 + c
  int c = idx & 63;
  const float* rd = &g_rad[(size_t)(idx>>6)*8];
  float a0=0.f, a1=0.f;
  #pragma unroll
  for(int b=0;b<8;b++){
    float rv = rd[b];
    a0 += rv*W1a[b*64+c];
    a1 += rv*W1b[b*64+c];
  }
  g_hb0[idx] = f2bf(silu(a0));
  g_hb1[idx] = f2bf(silu(a1));
}

// ---------------- W2 repack to B-frag layout (bf16) ----------------
template<int NCOLS>
__global__ void k_repack(const float* __restrict__ W2){
  constexpr int NCB = NCOLS/16;
  int t = blockIdx.x*256 + threadIdx.x;
  if(t >= NCB*128) return;
  int cb = t>>7, rest = t&127, ks = rest>>6, l = rest&63;
  int col = cb*16 + (l&15);
  unsigned short* dst = (NCOLS==832)? g_Bp1 : g_Bp0;
  #pragma unroll
  for(int j=0;j<8;j++){
    int k = ks*32 + ((l>>4)<<3) + j;
    dst[(size_t)t*8+j] = f2bf(W2[k*NCOLS + col]);
  }
}

// ---------------- fused layer-0 gather (MFMA w on the fly) ----------------
__global__ __launch_bounds__(256) void k_gfuse0(const float* __restrict__ wemb){
  __shared__ float lds_cg[36];
  __shared__ int lds_dec[9];
  __shared__ float Ylds[4][16][16];
  __shared__ float Glds[4][16][12];
  __shared__ int Slds[4][16];
  int tid=threadIdx.x;
  if(tid<36) lds_cg[tid]=g_cg[tid];
  if(tid>=64 && tid<73) lds_dec[tid-64]=g_dec[tid-64];
  __syncthreads();
  const int lane=tid&63, wid=tid>>6;
  const int sub=lane&15, kg=lane>>4;
  const int n=blockIdx.x*4+wid;
  const int beg=g_off[n], end=g_off[n+1];
  float acc[4][9];
  #pragma unroll
  for(int q=0;q<4;q++)
    #pragma unroll
    for(int k=0;k<9;k++) acc[q][k]=0.f;
  for(int j0=beg;j0<end;j0+=16){
    const int nrow = min(16,end-j0);
    for(int t=lane;t<256;t+=64){
      int r=t>>4, c2=t&15;
      int j=j0+r; if(j>end-1) j=end-1;
      Ylds[wid][r][c2]=g_ys[(size_t)j*16+c2];
    }
    if(lane<16){ int j=j0+lane; Slds[wid][lane]=(j<end)? g_specs[j] : 0; }
    asm volatile("s_waitcnt lgkmcnt(0)" ::: "memory");
    for(int t=lane;t<144;t+=64){
      int r=t/9, g=t-r*9;
      float gv=0.f;
      if(r<nrow){
        int d=lds_dec[g];
        int cgs=d&1023, yb=(d>>10)&15, d2=(d>>14)&7, d3=(d>>17)&7;
        for(int jj=0;jj<d2;jj++) gv+=Ylds[wid][r][yb+jj]*lds_cg[cgs+jj*d3];
      }
      Glds[wid][r][g]=gv;
    }
    size_t arow=(size_t)(j0+sub); if(arow>(size_t)(NE-1)) arow=NE-1;
    bf16x8 a0=*reinterpret_cast<const bf16x8*>(&g_hb0[arow*64 + kg*8]);
    bf16x8 a1=*reinterpret_cast<const bf16x8*>(&g_hb0[arow*64 + 32 + kg*8]);
    asm volatile("s_waitcnt lgkmcnt(0)" ::: "memory");
    #pragma unroll
    for(int cq=0;cq<4;cq++){
      const int c=cq*16+sub;
      float hv[4];
      #pragma unroll
      for(int r2=0;r2<4;r2++) hv[r2]=wemb[Slds[wid][kg*4+r2]*64+c];
      #pragma unroll
      for(int p=0;p<3;p++){
        const int cb=p*4+cq;
        bf16x8 b0=*reinterpret_cast<const bf16x8*>(&g_Bp0[((size_t)(cb*2+0)*64+lane)*8]);
        bf16x8 b1=*reinterpret_cast<const bf16x8*>(&g_Bp0[((size_t)(cb*2+1)*64+lane)*8]);
        f32x4 wv={0.f,0.f,0.f,0.f};
        wv=__builtin_amdgcn_mfma_f32_16x16x32_bf16(a0,b0,wv,0,0,0);
        wv=__builtin_amdgcn_mfma_f32_16x16x32_bf16(a1,b1,wv,0,0,0);
        const int d3=2*p+1, kb=KB[p], go=(p==0)?0:((p==1)?1:4);
        #pragma unroll
        for(int r2=0;r2<4;r2++){
          const int row=kg*4+r2;
          float whp=wv[r2]*hv[r2];
          #pragma unroll
          for(int k=0;k<d3;k++) acc[cq][kb+k]+=whp*Glds[wid][row][go+k];
        }
      }
    }
    asm volatile("s_waitcnt lgkmcnt(0)" ::: "memory");
  }
  #pragma unroll
  for(int q=0;q<4;q++)
    #pragma unroll
    for(int k=0;k<9;k++){
      float v=acc[q][k];
      v+=__shfl_xor(v,16,64);
      v+=__shfl_xor(v,32,64);
      acc[q][k]=v;
    }
  const int c=kg*16+sub;
  #pragma unroll
  for(int k=0;k<9;k++){
    float v=acc[0][k];
    if(kg==1) v=acc[1][k];
    if(kg==2) v=acc[2][k];
    if(kg==3) v=acc[3][k];
    g_acc0[(size_t)n*576 + k*64 + c]=v;
  }
}

// ---------------- fused layer-1 gather (MFMA w on the fly) ----------------
__global__ __launch_bounds__(256) void k_gfuse1(){
  __shared__ float lds_cg[CG_TOTAL];
  __shared__ int lds_dec[G_TOTAL];
  __shared__ float Ylds[4][16][16];
  __shared__ float Glds[4][16][148];
  int tid=threadIdx.x;
  for(int t=tid;t<CG_TOTAL;t+=256) lds_cg[t]=g_cg[t];
  for(int t=tid;t<G_TOTAL;t+=256) lds_dec[t]=g_dec[t];
  __syncthreads();
  const int lane=tid&63, wid=tid>>6;
  const int sub=lane&15, kg=lane>>4;
  const int n=blockIdx.x*4+wid;
  const int beg=g_off[n], end=g_off[n+1];
  float acc[4][9];
  #pragma unroll
  for(int q=0;q<4;q++)
    #pragma unroll
    for(int k=0;k<9;k++) acc[q][k]=0.f;
  for(int j0=beg;j0<end;j0+=16){
    const int nrow = min(16,end-j0);
    for(int t=lane;t<256;t+=64){
      int r=t>>4, c2=t&15;
      int j=j0+r; if(j>end-1) j=end-1;
      Ylds[wid][r][c2]=g_ys[(size_t)j*16+c2];
    }
    asm volatile("s_waitcnt lgkmcnt(0)" ::: "memory");
    for(int t=lane;t<16*G_TOTAL;t+=64){
      int r=t/G_TOTAL, g=t-r*G_TOTAL;
      float gv=0.f;
      if(r<nrow){
        int d=lds_dec[g];
        int cgs=d&1023, yb=(d>>10)&15, d2=(d>>14)&7, d3=(d>>17)&7;
        for(int jj=0;jj<d2;jj++) gv+=Ylds[wid][r][yb+jj]*lds_cg[cgs+jj*d3];
      }
      Glds[wid][r][g]=gv;
    }
    size_t arow=(size_t)(j0+sub); if(arow>(size_t)(NE-1)) arow=NE-1;
    bf16x8 a0=*reinterpret_cast<const bf16x8*>(&g_hb1[arow*64 + kg*8]);
    bf16x8 a1=*reinterpret_cast<const bf16x8*>(&g_hb1[arow*64 + 32 + kg*8]);
    int sv[4];
    #pragma unroll
    for(int r2=0;r2<4;r2++){ int j=j0+kg*4+r2; sv[r2]=(j<end)? g_snds[j] : 0; }
    asm volatile("s_waitcnt lgkmcnt(0)" ::: "memory");
    #pragma unroll
    for(int cq=0;cq<4;cq++){
      const int c=cq*16+sub;
      float h0v[4][9];
      #pragma unroll
      for(int r2=0;r2<4;r2++)
        #pragma unroll
        for(int i=0;i<9;i++) h0v[r2][i]=g_h0[(size_t)sv[r2]*576 + i*64 + c];
      #pragma unroll
      for(int p=0;p<13;p++){
        const int cb=p*4+cq;
        bf16x8 b0=*reinterpret_cast<const bf16x8*>(&g_Bp1[((size_t)(cb*2+0)*64+lane)*8]);
        bf16x8 b1=*reinterpret_cast<const bf16x8*>(&g_Bp1[((size_t)(cb*2+1)*64+lane)*8]);
        f32x4 wv={0.f,0.f,0.f,0.f};
        wv=__builtin_amdgcn_mfma_f32_16x16x32_bf16(a0,b0,wv,0,0,0);
        wv=__builtin_amdgcn_mfma_f32_16x16x32_bf16(a1,b1,wv,0,0,0);
        const int l1=c_l1[p], l3=c_l3[p];
        const int d1=2*l1+1, d3=2*l3+1;
        const int ib=IB[l1], kb=KB[l3], go=c_goff[p];
        #pragma unroll
        for(int r2=0;r2<4;r2++){
          const int row=kg*4+r2;
          float wp=wv[r2];
          #pragma unroll
          for(int k=0;k<d3;k++){
            float t=0.f;
            #pragma unroll
            for(int i=0;i<d1;i++) t+=h0v[r2][ib+i]*Glds[wid][row][go+i*d3+k];
            acc[cq][kb+k]+=wp*t;
          }
        }
      }
    }
    asm volatile("s_waitcnt lgkmcnt(0)" ::: "memory");
  }
  #pragma unroll
  for(int q=0;q<4;q++)
    #pragma unroll
    for(int k=0;k<9;k++){
      float v=acc[q][k];
      v+=__shfl_xor(v,16,64);
      v+=__shfl_xor(v,32,64);
      acc[q][k]=v;
    }
  const int c=kg*16+sub;
  #pragma unroll
  for(int k=0;k<9;k++){
    float v=acc[0][k];
    if(kg==1) v=acc[1][k];
    if(kg==2) v=acc[2][k];
    if(kg==3) v=acc[3][k];
    g_acc1[(size_t)n*576 + k*64 + c]=v;
  }
}

// ---------------- node update 0 (wave per node) ----------------
__global__ __launch_bounds__(256) void k_node0(const float* __restrict__ mix,
    const float* __restrict__ read, float* __restrict__ out){
  __shared__ float nm[4][9][64];
  __shared__ float hl[4][9][64];
  int lane=threadIdx.x&63, wid=threadIdx.x>>6;
  int n=blockIdx.x*4+wid;
  #pragma unroll
  for(int kk=0;kk<9;kk++) nm[wid][kk][lane]=g_acc0[(size_t)n*576+kk*64+lane]*(1.f/16.f);
  asm volatile("s_waitcnt lgkmcnt(0)" ::: "memory");
  float h[9];
  #pragma unroll
  for(int kk=0;kk<9;kk++) h[kk]=0.f;
  for(int c=0;c<64;c++){
    float m0=mix[c*64+lane], m1=mix[4096+c*64+lane], m2=mix[8192+c*64+lane];
    h[0]+=nm[wid][0][c]*m0;
    #pragma unroll
    for(int k=0;k<3;k++) h[1+k]+=nm[wid][1+k][c]*m1;
    #pragma unroll
    for(int k=0;k<5;k++) h[4+k]+=nm[wid][4+k][c]*m2;
  }
  #pragma unroll
  for(int kk=0;kk<9;kk++){ g_h0[(size_t)n*576+kk*64+lane]=h[kk]; hl[wid][kk][lane]=h[kk]; }
  asm volatile("s_waitcnt lgkmcnt(0)" ::: "memory");
  float o[9];
  #pragma unroll
  for(int kk=0;kk<9;kk++) o[kk]=0.f;
  for(int c=0;c<64;c++){
    float r0=read[c*64+lane], r1=read[4096+c*64+lane], r2=read[8192+c*64+lane];
    o[0]+=hl[wid][0][c]*r0;
    #pragma unroll
    for(int k=0;k<3;k++) o[1+k]+=hl[wid][1+k][c]*r1;
    #pragma unroll
    for(int k=0;k<5;k++) o[4+k]+=hl[wid][4+k][c]*r2;
  }
  float* op=&out[(size_t)n*1152];
  op[lane]=o[0];
  #pragma unroll
  for(int k=0;k<3;k++) op[64 + lane*3+k]=o[1+k];
  #pragma unroll
  for(int k=0;k<5;k++) op[256 + lane*5+k]=o[4+k];
}

// ---------------- node update 1 (wave per node) ----------------
__global__ __launch_bounds__(256) void k_node1(const float* __restrict__ mix,
    const float* __restrict__ skip, const float* __restrict__ read, float* __restrict__ out){
  __shared__ float nm[4][9][64];
  __shared__ float h0l[4][9][64];
  __shared__ float hn[4][9][64];
  int lane=threadIdx.x&63, wid=threadIdx.x>>6;
  int n=blockIdx.x*4+wid;
  #pragma unroll
  for(int kk=0;kk<9;kk++){
    nm[wid][kk][lane]=g_acc1[(size_t)n*576+kk*64+lane]*(1.f/16.f);
    h0l[wid][kk][lane]=g_h0[(size_t)n*576+kk*64+lane];
  }
  asm volatile("s_waitcnt lgkmcnt(0)" ::: "memory");
  float h[9];
  #pragma unroll
  for(int kk=0;kk<9;kk++) h[kk]=0.f;
  for(int c=0;c<64;c++){
    float m0=mix[c*64+lane], m1=mix[4096+c*64+lane], m2=mix[8192+c*64+lane];
    float s0=skip[c*64+lane], s1=skip[4096+c*64+lane], s2=skip[8192+c*64+lane];
    h[0]+=nm[wid][0][c]*m0 + h0l[wid][0][c]*s0;
    #pragma unroll
    for(int k=0;k<3;k++) h[1+k]+=nm[wid][1+k][c]*m1 + h0l[wid][1+k][c]*s1;
    #pragma unroll
    for(int k=0;k<5;k++) h[4+k]+=nm[wid][4+k][c]*m2 + h0l[wid][4+k][c]*s2;
  }
  #pragma unroll
  for(int kk=0;kk<9;kk++) hn[wid][kk][lane]=h[kk];
  asm volatile("s_waitcnt lgkmcnt(0)" ::: "memory");
  float o[9];
  #pragma unroll
  for(int kk=0;kk<9;kk++) o[kk]=0.f;
  for(int c=0;c<64;c++){
    float r0=read[c*64+lane], r1=read[4096+c*64+lane], r2=read[8192+c*64+lane];
    o[0]+=hn[wid][0][c]*r0;
    #pragma unroll
    for(int k=0;k<3;k++) o[1+k]+=hn[wid][1+k][c]*r1;
    #pragma unroll
    for(int k=0;k<5;k++) o[4+k]+=hn[wid][4+k][c]*r2;
  }
  float* op=&out[(size_t)n*1152 + 576];
  op[lane]=o[0];
  #pragma unroll
  for(int k=0;k<3;k++) op[64 + lane*3+k]=o[1+k];
  #pragma unroll
  for(int k=0;k<5;k++) op[256 + lane*5+k]=o[4+k];
}

extern "C" void kernel_launch(void* const* d_in, const int* in_sizes, int n_in,
                              void* d_out, int out_size, void* d_ws, size_t ws_size,
                              hipStream_t stream) {
  (void)in_sizes; (void)n_in; (void)out_size; (void)d_ws; (void)ws_size;
  const float* pos  =(const float*)d_in[0];
  const int*   spec =(const int*)  d_in[1];
  const int*   snd  =(const int*)  d_in[2];
  const int*   rcv  =(const int*)  d_in[3];
  const float* wemb =(const float*)d_in[4];
  const float* w1_0 =(const float*)d_in[5];
  const float* w2_0 =(const float*)d_in[6];
  const float* mix0 =(const float*)d_in[7];
  const float* read0=(const float*)d_in[8];
  const float* w1_1 =(const float*)d_in[9];
  const float* w2_1 =(const float*)d_in[10];
  const float* mix1 =(const float*)d_in[11];
  const float* skip1=(const float*)d_in[12];
  const float* read1=(const float*)d_in[13];
  float* out=(float*)d_out;

  k_cg<<<1,1024,0,stream>>>();
  k_zero<<<(NN+255)/256,256,0,stream>>>();
  k_hist<<<NE/256,256,0,stream>>>(rcv);
  k_scan<<<1,1024,0,stream>>>();
  k_scatter<<<NE/256,256,0,stream>>>(rcv,snd,spec);
  k_edge<<<(NE+255)/256,256,0,stream>>>(pos,snd,rcv);
  k_hidden<<<NE*64/256,256,0,stream>>>(w1_0,w1_1);
  k_repack<192><<<6,256,0,stream>>>(w2_0);
  k_repack<832><<<26,256,0,stream>>>(w2_1);
  k_gfuse0<<<NN/4,256,0,stream>>>(wemb);
  k_node0<<<NN/4,256,0,stream>>>(mix0,read0,out);
  k_gfuse1<<<NN/4,256,0,stream>>>();
  k_node1<<<NN/4,256,0,stream>>>(mix1,skip1,read1,out);
}

// Round 6
// 745.822 us; speedup vs baseline: 3.2707x; 3.2707x over previous
//
#include <hip/hip_runtime.h>
#include <math.h>

#define NE 160000
#define NN 10000
#define NP1 13
#define CG_TOTAL 573
#define CC_TOTAL 171
#define G_TOTAL 145
#define G1PAD 172   // per-edge padded G size, layer 1
#define G0PAD 16    // per-edge padded G size, layer 0

typedef __attribute__((ext_vector_type(8))) short bf16x8;
typedef __attribute__((ext_vector_type(4))) float f32x4;

// path metadata (l1,l2,l3) in reference enumeration order
constexpr int c_l1[NP1]   = {0,0,0,1,1,1,1,1,2,2,2,2,2};
constexpr int c_l2[NP1]   = {0,1,2,0,1,1,2,3,0,1,2,2,3};
constexpr int c_l3[NP1]   = {0,1,2,1,0,2,1,2,2,1,0,2,1};
constexpr int c_cgoff[NP1+1]= {0,1,10,35,44,53,98,143,248,273,318,343,468,573};
constexpr int c_ccoff[NP1+1]= {0,1,4,9,12,21,30,45,66,71,86,111,136,171};
// padded (16B-aligned) per-path offsets into the per-edge G record
constexpr int c_poff1[NP1] = {0,4,8,16,28,32,48,60,76,104,120,128,156};
constexpr int c_poff0[3]   = {0,4,8};
constexpr int YB[4] = {0,1,4,9};

// ---------------- static device scratch ----------------
__device__ float g_cg[640];
__device__ int   g_dec1[160];
__device__ int   g_dec0[16];
__device__ float g_ys[(size_t)NE*16];     // CSR order
__device__ float g_rad[(size_t)NE*8];     // CSR order
__device__ unsigned short g_hb0[(size_t)NE*64];  // CSR order
__device__ unsigned short g_hb1[(size_t)NE*64];  // CSR order
__device__ unsigned short g_Bp0[12*2*64*8];
__device__ unsigned short g_Bp1[52*2*64*8];
__device__ unsigned short g_W0[(size_t)NE*192];  // CSR order
__device__ unsigned short g_W1[(size_t)NE*832];  // CSR order
__device__ float g_G1[(size_t)NE*G1PAD];  // CSR order, padded per-path
__device__ float g_G0[(size_t)NE*G0PAD];
__device__ float g_acc0[(size_t)NN*576];
__device__ float g_acc1[(size_t)NN*576];
__device__ float g_h0[(size_t)NN*576];
__device__ int g_cnt[NN];
__device__ int g_cur[NN];
__device__ int g_off[NN+1];
__device__ int g_jof[NE];    // edge -> CSR slot
__device__ int g_snds[NE];   // CSR slot -> sender node
__device__ int g_specs[NE];  // CSR slot -> sender species

__device__ inline unsigned short f2bf(float f){
  unsigned u = __float_as_uint(f);
  unsigned r = (u + 0x7FFFu + ((u>>16)&1u)) >> 16;
  return (unsigned short)r;
}
__device__ inline float bf2f(unsigned short h){ return __uint_as_float(((unsigned)h)<<16); }
__device__ inline float silu(float a){ return a/(1.f+expf(-a)); }

// ---------------- CG computation (device, double, parallel) ----------------
__device__ double dfact(int n){ double f=1.0; for(int i=2;i<=n;++i) f*=(double)i; return f; }

__device__ double cg_coef(int j1,int m1,int j2,int m2,int j3,int m3){
  if(m1+m2!=m3) return 0.0;
  double pref = sqrt((2.0*j3+1.0)*dfact(j3+j1-j2)*dfact(j3-j1+j2)*dfact(j1+j2-j3)/dfact(j1+j2+j3+1));
  pref *= sqrt(dfact(j3+m3)*dfact(j3-m3)*dfact(j1-m1)*dfact(j1+m1)*dfact(j2-m2)*dfact(j2+m2));
  double s=0.0;
  for(int k=0;k<=j1+j2-j3;++k){
    int d0=k, d1=j1+j2-j3-k, d2=j1-m1-k, d3=j2+m2-k, d4=j3-j2+m1+k, d5=j3-j1-m2+k;
    if(d1<0||d2<0||d3<0||d4<0||d5<0) continue;
    double denom = dfact(d0)*dfact(d1)*dfact(d2)*dfact(d3)*dfact(d4)*dfact(d5);
    s += ((k&1)? -1.0:1.0)/denom;
  }
  return pref*s;
}

__device__ inline void rb_elem(int l, int i, int j, double& re, double& im){
  re=0.0; im=0.0;
  int mp = i - l;
  const double is2 = 0.70710678118654752440;
  if(mp>0){
    if(j==l+mp) re = ((mp&1)? -1.0:1.0)*is2;
    else if(j==l-mp) re = is2;
  } else if(mp==0){
    if(j==l) re = 1.0;
  } else {
    int m=-mp;
    if(j==l-m) im = is2;
    else if(j==l+m) im = -(((m&1)?-1.0:1.0))*is2;
  }
}

__global__ __launch_bounds__(1024) void k_cg(){
  __shared__ double s_cc[CC_TOTAL];
  __shared__ double s_crr[CG_TOTAL];
  __shared__ double s_cri[CG_TOTAL];
  __shared__ double s_inv[NP1];
  __shared__ int    s_useR[NP1];
  int tid = threadIdx.x;

  if(tid==0){
    int r=0;
    for(int q=0;q<NP1;q++){
      int l2=c_l2[q], l3=c_l3[q];
      int d1=2*c_l1[q]+1, d2=2*l2+1, d3=2*l3+1;
      for(int i=0;i<d1;i++)for(int k=0;k<d3;k++){
        int cgs = c_cgoff[q] + i*d2*d3 + k;
        int dst = c_poff1[q] + i*d3 + k;
        g_dec1[r++] = cgs | (YB[l2]<<10) | (d2<<14) | (d3<<17) | (dst<<20);
      }
    }
    r=0;
    for(int q=0;q<3;q++){
      int l2=c_l2[q], l3=c_l3[q];
      int d2=2*l2+1, d3=2*l3+1;
      for(int k=0;k<d3;k++){
        int cgs = c_cgoff[q] + k;
        int dst = c_poff0[q] + k;
        g_dec0[r++] = cgs | (YB[l2]<<10) | (d2<<14) | (d3<<17) | (dst<<20);
      }
    }
  }

  if(tid < CC_TOTAL){
    int p=0; while(tid >= c_ccoff[p+1]) p++;
    int r = tid - c_ccoff[p];
    int l1=c_l1[p], l2=c_l2[p], l3=c_l3[p];
    int d2=2*l2+1;
    int ai = r/d2, bi = r - ai*d2;
    int a = ai - l1, b = bi - l2, c = a + b;
    double v = 0.0;
    if(c >= -l3 && c <= l3) v = cg_coef(l1,a,l2,b,l3,c);
    s_cc[tid] = v;
  }
  __syncthreads();

  if(tid < CG_TOTAL){
    int p=0; while(tid >= c_cgoff[p+1]) p++;
    int r = tid - c_cgoff[p];
    int l1=c_l1[p], l2=c_l2[p], l3=c_l3[p];
    int d2=2*l2+1, d3=2*l3+1;
    int i = r/(d2*d3), rem = r - i*(d2*d3);
    int j = rem/d3, k = rem - j*d3;
    double accr=0.0, acci=0.0;
    int d1=2*l1+1;
    for(int ai=0; ai<d1; ai++){
      double a1r,a1i; rb_elem(l1,i,ai,a1r,a1i);
      if(a1r==0.0 && a1i==0.0) continue;
      for(int bi=0; bi<d2; bi++){
        double cc = s_cc[c_ccoff[p] + ai*d2 + bi];
        if(cc==0.0) continue;
        int ci = (ai - l1) + (bi - l2) + l3;
        if(ci < 0 || ci >= d3) continue;
        double a2r,a2i; rb_elem(l2,j,bi,a2r,a2i);
        if(a2r==0.0 && a2i==0.0) continue;
        double a3r,a3i; rb_elem(l3,k,ci,a3r,a3i);
        a3i = -a3i;
        double p12r = a1r*a2r - a1i*a2i;
        double p12i = a1r*a2i + a1i*a2r;
        accr += (p12r*a3r - p12i*a3i)*cc;
        acci += (p12r*a3i + p12i*a3r)*cc;
      }
    }
    s_crr[tid] = accr;
    s_cri[tid] = acci;
  }
  __syncthreads();

  if(tid < NP1){
    int beg=c_cgoff[tid], end=c_cgoff[tid+1];
    double sr=0.0, si=0.0;
    for(int t=beg;t<end;t++){ sr += fabs(s_crr[t]); si += fabs(s_cri[t]); }
    int useR = (sr>=si);
    double nrm=0.0;
    for(int t=beg;t<end;t++){ double v = useR? s_crr[t] : s_cri[t]; nrm += v*v; }
    nrm = sqrt(nrm); if(nrm<1e-12) nrm=1e-12;
    s_useR[tid]=useR; s_inv[tid]=1.0/nrm;
  }
  __syncthreads();

  if(tid < CG_TOTAL){
    int p=0; while(tid >= c_cgoff[p+1]) p++;
    double v = s_useR[p]? s_crr[tid] : s_cri[tid];
    g_cg[tid] = (float)(v*s_inv[p]);
  }
}

// ---------------- CSR build ----------------
__global__ void k_zero(){
  int i = blockIdx.x*256 + threadIdx.x;
  if(i<NN){ g_cnt[i]=0; g_cur[i]=0; }
}

__global__ void k_hist(const int* __restrict__ rcv){
  int e = blockIdx.x*256 + threadIdx.x;
  if(e<NE) atomicAdd(&g_cnt[rcv[e]], 1);
}

__global__ void k_scan(){
  __shared__ int lds[1024];
  int t = threadIdx.x;
  int base = t*10;
  int s = 0;
  for(int i=0;i<10;i++){ int idx=base+i; if(idx<NN) s += g_cnt[idx]; }
  lds[t]=s; __syncthreads();
  for(int o=1;o<1024;o<<=1){
    int v = (t>=o)? lds[t-o] : 0;
    __syncthreads();
    lds[t]+=v;
    __syncthreads();
  }
  int run = lds[t]-s;
  for(int i=0;i<10;i++){ int idx=base+i; if(idx<NN){ g_off[idx]=run; run+=g_cnt[idx]; } }
  if(t==0) g_off[NN]=NE;
}

__global__ void k_scatter(const int* __restrict__ rcv, const int* __restrict__ snd,
                          const int* __restrict__ spec){
  int e = blockIdx.x*256 + threadIdx.x;
  if(e<NE){
    int r = rcv[e];
    int p = atomicAdd(&g_cur[r],1);
    int j = g_off[r]+p;
    g_jof[e] = j;
    int s = snd[e];
    g_snds[j] = s;
    g_specs[j] = spec[s];
  }
}

// ---------------- edge geometry + radial basis (writes CSR slots) ----------------
__global__ void k_edge(const float* __restrict__ pos, const int* __restrict__ snd,
                       const int* __restrict__ rcv){
  int e = blockIdx.x*blockDim.x + threadIdx.x;
  if(e>=NE) return;
  int s=snd[e], r=rcv[e];
  int j=g_jof[e];
  float dx=pos[r*3+0]-pos[s*3+0];
  float dy=pos[r*3+1]-pos[s*3+1];
  float dz=pos[r*3+2]-pos[s*3+2];
  float rr = sqrtf(dx*dx+dy*dy+dz*dz + 1e-12f);
  float x=dx/rr, y=dy/rr, z=dz/rr;
  float Y[16];
  Y[0]=1.f;
  const float s3=1.7320508075688772f;
  Y[1]=s3*y; Y[2]=s3*z; Y[3]=s3*x;
  const float s15=3.872983346207417f;
  const float s5h=1.118033988749895f;
  Y[4]=s15*x*y; Y[5]=s15*y*z; Y[6]=s5h*(3.f*z*z-1.f); Y[7]=s15*x*z; Y[8]=0.5f*s15*(x*x-y*y);
  const float s35_8=2.0916500663351889f;
  const float s105=10.246950765959598f;
  const float s21_8=1.6201851746019651f;
  const float s7h=1.3228756555322954f;
  Y[9]=s35_8*y*(3.f*x*x-y*y);
  Y[10]=s105*x*y*z;
  Y[11]=s21_8*y*(5.f*z*z-1.f);
  Y[12]=s7h*z*(5.f*z*z-3.f);
  Y[13]=s21_8*x*(5.f*z*z-1.f);
  Y[14]=0.5f*s105*z*(x*x-y*y);
  Y[15]=s35_8*x*(x*x-3.f*y*y);
  #pragma unroll
  for(int i=0;i<16;i++) g_ys[(size_t)j*16+i]=Y[i];
  float t = 2.f*(1.f - rr*0.2f);
  float env = (t>0.f)? 1.9784655248401538f*expf(-1.f/t) : 0.f;
  float rs = fmaxf(rr,1e-6f);
  const float sq25 = 0.6324555320336759f;
  float pre = sq25/rs * env;
  const float pi5 = 0.6283185307179586f;
  #pragma unroll
  for(int b=0;b<8;b++){
    g_rad[(size_t)j*8+b] = pre * sinf((float)(b+1)*pi5*rs);
  }
}

// ---------------- G tables build: 8 edges per wave ----------------
__global__ __launch_bounds__(256) void k_gbuild(){
  __shared__ float cg[CG_TOTAL];
  __shared__ int dec1[G_TOTAL];
  __shared__ int dec0[9];
  __shared__ __align__(16) float Yl[4][8][17];
  __shared__ __align__(16) float Gl[4][8][G1PAD];
  __shared__ __align__(16) float G0l[4][8][G0PAD];
  int tid=threadIdx.x;
  for(int t=tid;t<CG_TOTAL;t+=256) cg[t]=g_cg[t];
  for(int t=tid;t<G_TOTAL;t+=256) dec1[t]=g_dec1[t];
  if(tid<9) dec0[tid]=g_dec0[tid];
  __syncthreads();
  const int lane=tid&63, wid=tid>>6;
  const int e0=blockIdx.x*32 + wid*8;
  // stage Y (8 edges x 16, coalesced; NE divisible by 32 so no guard)
  #pragma unroll
  for(int t=lane;t<128;t+=64){
    int r=t>>4, c=t&15;
    Yl[wid][r][c]=g_ys[(size_t)(e0+r)*16+c];
  }
  asm volatile("s_waitcnt lgkmcnt(0)" ::: "memory");
  // layer-1 G: 8*145 = 1160 entries
  for(int s=0;s<19;s++){
    int idx = lane + 64*s;
    if(idx<1160){
      int e = idx/145, r = idx - 145*e;
      int d = dec1[r];
      int cgs=d&1023, yb=(d>>10)&15, d2=(d>>14)&7, d3n=(d>>17)&7, dst=(d>>20)&255;
      float g=0.f;
      for(int jj=0;jj<d2;jj++) g += Yl[wid][e][yb+jj]*cg[cgs+jj*d3n];
      Gl[wid][e][dst]=g;
    }
  }
  // layer-0 G: 8*9 = 72 entries (strided: 72 > 64 lanes!)
  for(int idx=lane; idx<72; idx+=64){
    int e = idx/9, r = idx - 9*e;
    int d = dec0[r];
    int cgs=d&1023, yb=(d>>10)&15, d2=(d>>14)&7, d3n=(d>>17)&7, dst=(d>>20)&255;
    float g=0.f;
    for(int jj=0;jj<d2;jj++) g += Yl[wid][e][yb+jj]*cg[cgs+jj*d3n];
    G0l[wid][e][dst]=g;
  }
  asm volatile("s_waitcnt lgkmcnt(0)" ::: "memory");
  // flush (coalesced vec4): 8*172 = 1376 floats = 344 vec4
  {
    f32x4* dst=(f32x4*)&g_G1[(size_t)e0*G1PAD];
    const f32x4* src=(const f32x4*)&Gl[wid][0][0];
    for(int t=lane;t<344;t+=64) dst[t]=src[t];
  }
  {
    f32x4* dst=(f32x4*)&g_G0[(size_t)e0*G0PAD];
    const f32x4* src=(const f32x4*)&G0l[wid][0][0];
    if(lane<32) dst[lane]=src[lane];
  }
}

// ---------------- hidden = silu(rad@W1), bf16, CSR order ----------------
__global__ __launch_bounds__(256) void k_hidden(const float* __restrict__ W1a,
                                                const float* __restrict__ W1b){
  int idx = blockIdx.x*256 + threadIdx.x;   // idx = slot*64 + c
  int c = idx & 63;
  const float* rd = &g_rad[(size_t)(idx>>6)*8];
  float a0=0.f, a1=0.f;
  #pragma unroll
  for(int b=0;b<8;b++){
    float rv = rd[b];
    a0 += rv*W1a[b*64+c];
    a1 += rv*W1b[b*64+c];
  }
  g_hb0[idx] = f2bf(silu(a0));
  g_hb1[idx] = f2bf(silu(a1));
}

// ---------------- W2 repack to B-frag layout (bf16) ----------------
template<int NCOLS>
__global__ void k_repack(const float* __restrict__ W2){
  constexpr int NCB = NCOLS/16;
  int t = blockIdx.x*256 + threadIdx.x;
  if(t >= NCB*128) return;
  int cb = t>>7, rest = t&127, ks = rest>>6, l = rest&63;
  int col = cb*16 + (l&15);
  unsigned short* dst = (NCOLS==832)? g_Bp1 : g_Bp0;
  #pragma unroll
  for(int j=0;j<8;j++){
    int k = ks*32 + ((l>>4)<<3) + j;
    dst[(size_t)t*8+j] = f2bf(W2[k*NCOLS + col]);
  }
}

// ---------------- W = hidden @ W2 via MFMA (bf16 in, bf16 out) ----------------
template<int NCOLS>
__global__ __launch_bounds__(256) void k_wgemm(){
  constexpr int NCB = NCOLS/16;
  const unsigned short* hb = (NCOLS==832)? g_hb1 : g_hb0;
  const unsigned short* Bp = (NCOLS==832)? g_Bp1 : g_Bp0;
  unsigned short* W = (NCOLS==832)? g_W1 : g_W0;
  const int lane = threadIdx.x & 63;
  const int wid  = threadIdx.x >> 6;
  const int e0 = blockIdx.x*128 + wid*32;   // 32 edges per wave
  const int rowl = lane & 15, kg = lane >> 4;
  bf16x8 a[2][2];
  #pragma unroll
  for(int mr=0;mr<2;mr++){
    #pragma unroll
    for(int ks=0;ks<2;ks++){
      a[mr][ks] = *reinterpret_cast<const bf16x8*>(&hb[(size_t)(e0+mr*16+rowl)*64 + ks*32 + kg*8]);
    }
  }
  for(int cb=0;cb<NCB;cb++){
    bf16x8 b0 = *reinterpret_cast<const bf16x8*>(&Bp[((size_t)(cb*2+0)*64+lane)*8]);
    bf16x8 b1 = *reinterpret_cast<const bf16x8*>(&Bp[((size_t)(cb*2+1)*64+lane)*8]);
    #pragma unroll
    for(int mr=0;mr<2;mr++){
      f32x4 acc = {0.f,0.f,0.f,0.f};
      acc = __builtin_amdgcn_mfma_f32_16x16x32_bf16(a[mr][0], b0, acc, 0,0,0);
      acc = __builtin_amdgcn_mfma_f32_16x16x32_bf16(a[mr][1], b1, acc, 0,0,0);
      #pragma unroll
      for(int r=0;r<4;r++){
        int row = kg*4 + r;
        W[(size_t)(e0+mr*16+row)*NCOLS + cb*16 + rowl] = f2bf(acc[r]);
      }
    }
  }
}

// ---------------- layer-0 gather (no LDS; lane = channel) ----------------
__global__ __launch_bounds__(256) void k_gather0(const float* __restrict__ wemb){
  const int lane=threadIdx.x&63, wid=threadIdx.x>>6;
  const int n=blockIdx.x*4+wid;
  const int beg=__builtin_amdgcn_readfirstlane(g_off[n]);
  const int end=__builtin_amdgcn_readfirstlane(g_off[n+1]);
  float acc[9];
  #pragma unroll
  for(int k=0;k<9;k++) acc[k]=0.f;
  for(int j=beg;j<end;j++){
    const float* Ge=&g_G0[(size_t)j*G0PAD];
    f32x4 qa=*reinterpret_cast<const f32x4*>(Ge+0);
    f32x4 qb=*reinterpret_cast<const f32x4*>(Ge+4);
    f32x4 qc=*reinterpret_cast<const f32x4*>(Ge+8);
    f32x4 qd=*reinterpret_cast<const f32x4*>(Ge+12);
    int sp=__builtin_amdgcn_readfirstlane(g_specs[j]);
    float hs=wemb[sp*64+lane];
    const unsigned short* wp=&g_W0[(size_t)j*192 + lane];
    float a0=bf2f(wp[0])*hs, a1=bf2f(wp[64])*hs, a2=bf2f(wp[128])*hs;
    acc[0]+=a0*qa[0];
    acc[1]+=a1*qb[0]; acc[2]+=a1*qb[1]; acc[3]+=a1*qb[2];
    acc[4]+=a2*qc[0]; acc[5]+=a2*qc[1]; acc[6]+=a2*qc[2]; acc[7]+=a2*qc[3];
    acc[8]+=a2*qd[0];
  }
  #pragma unroll
  for(int k=0;k<9;k++) g_acc0[(size_t)n*576 + k*64 + lane]=acc[k];
}

// per-path contraction macro: compile-time (P, l1, l3, padded offset)
#define DP(P_,L1_,L3_,OFF_) { \
  constexpr int d1_=2*(L1_)+1, d3_=2*(L3_)+1, ib_=(L1_)*(L1_), kb_=(L3_)*(L3_); \
  constexpr int nv_=((d1_*d3_)+3)/4; \
  f32x4 gq[nv_]; \
  _Pragma("unroll") \
  for(int q_=0;q_<nv_;q_++) gq[q_]=*reinterpret_cast<const f32x4*>(Ge+(OFF_)+4*q_); \
  _Pragma("unroll") \
  for(int k_=0;k_<d3_;k_++){ \
    float tk_=0.f; \
    _Pragma("unroll") \
    for(int i_=0;i_<d1_;i_++){ tk_+=h[ib_+i_]*gq[(i_*d3_+k_)>>2][(i_*d3_+k_)&3]; } \
    acc[kb_+k_]+=w[P_]*tk_; } }

// ---------------- layer-1 gather (no LDS; lane = channel) ----------------
__global__ __launch_bounds__(256) void k_gather1(){
  const int lane=threadIdx.x&63, wid=threadIdx.x>>6;
  const int n=blockIdx.x*4+wid;
  const int beg=__builtin_amdgcn_readfirstlane(g_off[n]);
  const int end=__builtin_amdgcn_readfirstlane(g_off[n+1]);
  float acc[9];
  #pragma unroll
  for(int k=0;k<9;k++) acc[k]=0.f;
  for(int j=beg;j<end;j++){
    const int s=__builtin_amdgcn_readfirstlane(g_snds[j]);
    const float* Ge=&g_G1[(size_t)j*G1PAD];
    float h[9];
    #pragma unroll
    for(int i=0;i<9;i++) h[i]=g_h0[(size_t)s*576 + i*64 + lane];
    const unsigned short* wp=&g_W1[(size_t)j*832 + lane];
    float w[13];
    #pragma unroll
    for(int p=0;p<13;p++) w[p]=bf2f(wp[p*64]);
    DP(0,0,0,0)
    DP(1,0,1,4)
    DP(2,0,2,8)
    DP(3,1,1,16)
    DP(4,1,0,28)
    DP(5,1,2,32)
    DP(6,1,1,48)
    DP(7,1,2,60)
    DP(8,2,2,76)
    DP(9,2,1,104)
    DP(10,2,0,120)
    DP(11,2,2,128)
    DP(12,2,1,156)
  }
  #pragma unroll
  for(int k=0;k<9;k++) g_acc1[(size_t)n*576 + k*64 + lane]=acc[k];
}

// ---------------- node update 0 (wave per node) ----------------
__global__ __launch_bounds__(256) void k_node0(const float* __restrict__ mix,
    const float* __restrict__ read, float* __restrict__ out){
  __shared__ float nm[4][9][64];
  __shared__ float hl[4][9][64];
  int lane=threadIdx.x&63, wid=threadIdx.x>>6;
  int n=blockIdx.x*4+wid;
  #pragma unroll
  for(int kk=0;kk<9;kk++) nm[wid][kk][lane]=g_acc0[(size_t)n*576+kk*64+lane]*(1.f/16.f);
  asm volatile("s_waitcnt lgkmcnt(0)" ::: "memory");
  float h[9];
  #pragma unroll
  for(int kk=0;kk<9;kk++) h[kk]=0.f;
  for(int c=0;c<64;c++){
    float m0=mix[c*64+lane], m1=mix[4096+c*64+lane], m2=mix[8192+c*64+lane];
    h[0]+=nm[wid][0][c]*m0;
    #pragma unroll
    for(int k=0;k<3;k++) h[1+k]+=nm[wid][1+k][c]*m1;
    #pragma unroll
    for(int k=0;k<5;k++) h[4+k]+=nm[wid][4+k][c]*m2;
  }
  #pragma unroll
  for(int kk=0;kk<9;kk++){ g_h0[(size_t)n*576+kk*64+lane]=h[kk]; hl[wid][kk][lane]=h[kk]; }
  asm volatile("s_waitcnt lgkmcnt(0)" ::: "memory");
  float o[9];
  #pragma unroll
  for(int kk=0;kk<9;kk++) o[kk]=0.f;
  for(int c=0;c<64;c++){
    float r0=read[c*64+lane], r1=read[4096+c*64+lane], r2=read[8192+c*64+lane];
    o[0]+=hl[wid][0][c]*r0;
    #pragma unroll
    for(int k=0;k<3;k++) o[1+k]+=hl[wid][1+k][c]*r1;
    #pragma unroll
    for(int k=0;k<5;k++) o[4+k]+=hl[wid][4+k][c]*r2;
  }
  float* op=&out[(size_t)n*1152];
  op[lane]=o[0];
  #pragma unroll
  for(int k=0;k<3;k++) op[64 + lane*3+k]=o[1+k];
  #pragma unroll
  for(int k=0;k<5;k++) op[256 + lane*5+k]=o[4+k];
}

// ---------------- node update 1 (wave per node) ----------------
__global__ __launch_bounds__(256) void k_node1(const float* __restrict__ mix,
    const float* __restrict__ skip, const float* __restrict__ read, float* __restrict__ out){
  __shared__ float nm[4][9][64];
  __shared__ float h0l[4][9][64];
  __shared__ float hn[4][9][64];
  int lane=threadIdx.x&63, wid=threadIdx.x>>6;
  int n=blockIdx.x*4+wid;
  #pragma unroll
  for(int kk=0;kk<9;kk++){
    nm[wid][kk][lane]=g_acc1[(size_t)n*576+kk*64+lane]*(1.f/16.f);
    h0l[wid][kk][lane]=g_h0[(size_t)n*576+kk*64+lane];
  }
  asm volatile("s_waitcnt lgkmcnt(0)" ::: "memory");
  float h[9];
  #pragma unroll
  for(int kk=0;kk<9;kk++) h[kk]=0.f;
  for(int c=0;c<64;c++){
    float m0=mix[c*64+lane], m1=mix[4096+c*64+lane], m2=mix[8192+c*64+lane];
    float s0=skip[c*64+lane], s1=skip[4096+c*64+lane], s2=skip[8192+c*64+lane];
    h[0]+=nm[wid][0][c]*m0 + h0l[wid][0][c]*s0;
    #pragma unroll
    for(int k=0;k<3;k++) h[1+k]+=nm[wid][1+k][c]*m1 + h0l[wid][1+k][c]*s1;
    #pragma unroll
    for(int k=0;k<5;k++) h[4+k]+=nm[wid][4+k][c]*m2 + h0l[wid][4+k][c]*s2;
  }
  #pragma unroll
  for(int kk=0;kk<9;kk++) hn[wid][kk][lane]=h[kk];
  asm volatile("s_waitcnt lgkmcnt(0)" ::: "memory");
  float o[9];
  #pragma unroll
  for(int kk=0;kk<9;kk++) o[kk]=0.f;
  for(int c=0;c<64;c++){
    float r0=read[c*64+lane], r1=read[4096+c*64+lane], r2=read[8192+c*64+lane];
    o[0]+=hn[wid][0][c]*r0;
    #pragma unroll
    for(int k=0;k<3;k++) o[1+k]+=hn[wid][1+k][c]*r1;
    #pragma unroll
    for(int k=0;k<5;k++) o[4+k]+=hn[wid][4+k][c]*r2;
  }
  float* op=&out[(size_t)n*1152 + 576];
  op[lane]=o[0];
  #pragma unroll
  for(int k=0;k<3;k++) op[64 + lane*3+k]=o[1+k];
  #pragma unroll
  for(int k=0;k<5;k++) op[256 + lane*5+k]=o[4+k];
}

extern "C" void kernel_launch(void* const* d_in, const int* in_sizes, int n_in,
                              void* d_out, int out_size, void* d_ws, size_t ws_size,
                              hipStream_t stream) {
  (void)in_sizes; (void)n_in; (void)out_size; (void)d_ws; (void)ws_size;
  const float* pos  =(const float*)d_in[0];
  const int*   spec =(const int*)  d_in[1];
  const int*   snd  =(const int*)  d_in[2];
  const int*   rcv  =(const int*)  d_in[3];
  const float* wemb =(const float*)d_in[4];
  const float* w1_0 =(const float*)d_in[5];
  const float* w2_0 =(const float*)d_in[6];
  const float* mix0 =(const float*)d_in[7];
  const float* read0=(const float*)d_in[8];
  const float* w1_1 =(const float*)d_in[9];
  const float* w2_1 =(const float*)d_in[10];
  const float* mix1 =(const float*)d_in[11];
  const float* skip1=(const float*)d_in[12];
  const float* read1=(const float*)d_in[13];
  float* out=(float*)d_out;

  k_cg<<<1,1024,0,stream>>>();
  k_zero<<<(NN+255)/256,256,0,stream>>>();
  k_hist<<<NE/256,256,0,stream>>>(rcv);
  k_scan<<<1,1024,0,stream>>>();
  k_scatter<<<NE/256,256,0,stream>>>(rcv,snd,spec);
  k_edge<<<(NE+255)/256,256,0,stream>>>(pos,snd,rcv);
  k_gbuild<<<NE/32,256,0,stream>>>();
  k_hidden<<<NE*64/256,256,0,stream>>>(w1_0,w1_1);
  k_repack<192><<<6,256,0,stream>>>(w2_0);
  k_repack<832><<<26,256,0,stream>>>(w2_1);
  k_wgemm<192><<<NE/128,256,0,stream>>>();
  k_wgemm<832><<<NE/128,256,0,stream>>>();
  k_gather0<<<NN/4,256,0,stream>>>(wemb);
  k_node0<<<NN/4,256,0,stream>>>(mix0,read0,out);
  k_gather1<<<NN/4,256,0,stream>>>();
  k_node1<<<NN/4,256,0,stream>>>(mix1,skip1,read1,out);
}